// Round 9
// baseline (29.993 us; speedup 1.0000x reference)
//
#include <hip/hip_runtime.h>
#include <math.h>

namespace {

constexpr int NB = 8;     // batch
constexpr int NS = 48;    // samples
constexpr int NA = 8192;  // atoms
constexpr int TPB = 256;  // 4 waves/block
constexpr int NW = TPB / 64;
constexpr int NBS = NB * NS;  // 384 blocks, one per (b,s)

// ws layout (floats): [0 .. NBS) per-(b,s) scalar contribution

// Kernel 1: self-sufficient per-(b,s) block. Computes the 13 per-sample sums
// AND the 6 per-b stats redundantly (same loaded data -> zero extra traffic),
// block-reduces, then thread 0 eigen-solves its own 3x3 (float trig; runs in
// parallel across 384 CUs) and writes one float contribution.
__global__ __launch_bounds__(TPB) void loss_kernel(
    const float* __restrict__ pred, const float* __restrict__ truec,
    const int* __restrict__ mask, const int* __restrict__ dna,
    const int* __restrict__ rna, const int* __restrict__ lig,
    const float* __restrict__ scale, float* __restrict__ ws) {
  const int bs = blockIdx.x;
  const int b = bs / NS;

  const float* p = pred + (size_t)bs * NA * 3;
  const float* t = truec + (size_t)b * NA * 3;
  const int mbase = b * NA;

  float acc[13];
#pragma unroll
  for (int k = 0; k < 13; ++k) acc[k] = 0.f;
  float accb[6];
#pragma unroll
  for (int k = 0; k < 6; ++k) accb[k] = 0.f;

  auto wgt = [](int m, int d, int r, int l) {
    return (float)((1 + 5 * (d + r) + 10 * l) * m);
  };
  auto atom = [&](float mf, float w, float p0, float p1, float p2, float t0,
                  float t1, float t2) {
    const float wp0 = w * p0, wp1 = w * p1, wp2 = w * p2;
    acc[0] += wp0 * p0 + wp1 * p1 + wp2 * p2;
    acc[1] += wp0;
    acc[2] += wp1;
    acc[3] += wp2;
    acc[4] += wp0 * t0;
    acc[5] += wp0 * t1;
    acc[6] += wp0 * t2;
    acc[7] += wp1 * t0;
    acc[8] += wp1 * t1;
    acc[9] += wp1 * t2;
    acc[10] += wp2 * t0;
    acc[11] += wp2 * t1;
    acc[12] += wp2 * t2;
    accb[0] += w;
    accb[1] += w * t0;
    accb[2] += w * t1;
    accb[3] += w * t2;
    accb[4] += w * (t0 * t0 + t1 * t1 + t2 * t2);
    accb[5] += mf;
  };

#pragma unroll
  for (int it = 0; it < NA / (TPB * 4); ++it) {  // 8 iters x 4 atoms
    const int n0 = it * (TPB * 4) + threadIdx.x * 4;
    const float4 pa = *(const float4*)(p + 3 * n0);
    const float4 pb = *(const float4*)(p + 3 * n0 + 4);
    const float4 pc = *(const float4*)(p + 3 * n0 + 8);
    const float4 ta = *(const float4*)(t + 3 * n0);
    const float4 tb = *(const float4*)(t + 3 * n0 + 4);
    const float4 tc = *(const float4*)(t + 3 * n0 + 8);
    const int4 mk = *(const int4*)(mask + mbase + n0);
    const int4 dn = *(const int4*)(dna + mbase + n0);
    const int4 rn = *(const int4*)(rna + mbase + n0);
    const int4 lg = *(const int4*)(lig + mbase + n0);

    atom((float)mk.x, wgt(mk.x, dn.x, rn.x, lg.x), pa.x, pa.y, pa.z, ta.x, ta.y, ta.z);
    atom((float)mk.y, wgt(mk.y, dn.y, rn.y, lg.y), pa.w, pb.x, pb.y, ta.w, tb.x, tb.y);
    atom((float)mk.z, wgt(mk.z, dn.z, rn.z, lg.z), pb.z, pb.w, pc.x, tb.z, tb.w, tc.x);
    atom((float)mk.w, wgt(mk.w, dn.w, rn.w, lg.w), pc.y, pc.z, pc.w, tc.y, tc.z, tc.w);
  }

  // block-reduce 19 values
  __shared__ float lds[NW][19];
  __shared__ float sums[19];
  const int lane = threadIdx.x & 63;
  const int wave = threadIdx.x >> 6;
#pragma unroll
  for (int k = 0; k < 19; ++k) {
    float x = (k < 13) ? acc[k] : accb[k - 13];
#pragma unroll
    for (int off = 32; off; off >>= 1) x += __shfl_xor(x, off, 64);
    if (lane == 0) lds[wave][k] = x;
  }
  __syncthreads();
  if ((int)threadIdx.x < 19) {
    float s = 0.f;
#pragma unroll
    for (int w = 0; w < NW; ++w) s += lds[w][threadIdx.x];
    sums[threadIdx.x] = s;
  }
  __syncthreads();

  if (threadIdx.x == 0) {
    const double wsum = (double)sums[13];
    const double St[3] = {(double)sums[14], (double)sums[15], (double)sums[16]};
    const double stt = (double)sums[17];
    const double msum = (double)sums[18];

    const double spp = (double)sums[0];
    const double Sp[3] = {(double)sums[1], (double)sums[2], (double)sums[3]};
    const double inv = 1.0 / wsum;

    double H[3][3];
#pragma unroll
    for (int i = 0; i < 3; ++i)
#pragma unroll
      for (int j = 0; j < 3; ++j)
        H[i][j] = (double)sums[4 + 3 * i + j] - Sp[i] * St[j] * inv;

    const double Sq = spp - (Sp[0] * Sp[0] + Sp[1] * Sp[1] + Sp[2] * Sp[2]) * inv;
    const double Sy = stt - (St[0] * St[0] + St[1] * St[1] + St[2] * St[2]) * inv;

    double K[3][3];
#pragma unroll
    for (int i = 0; i < 3; ++i)
#pragma unroll
      for (int j = 0; j < 3; ++j)
        K[i][j] = H[0][i] * H[0][j] + H[1][i] * H[1][j] + H[2][i] * H[2][j];

    const double q = (K[0][0] + K[1][1] + K[2][2]) / 3.0;
    const double p1 = K[0][1] * K[0][1] + K[0][2] * K[0][2] + K[1][2] * K[1][2];
    const double a0 = K[0][0] - q, a1 = K[1][1] - q, a2 = K[2][2] - q;
    const double p2 = a0 * a0 + a1 * a1 + a2 * a2 + 2.0 * p1;
    double e1, e2, e3;
    if (p2 <= 1e-300) {
      e1 = e2 = e3 = q;
    } else {
      const double pp = sqrt(p2 / 6.0);
      const double ip = 1.0 / pp;
      const double B00 = a0 * ip, B11 = a1 * ip, B22 = a2 * ip;
      const double B01 = K[0][1] * ip, B02 = K[0][2] * ip, B12 = K[1][2] * ip;
      double r = 0.5 * (B00 * (B11 * B22 - B12 * B12) - B01 * (B01 * B22 - B12 * B02) +
                        B02 * (B01 * B12 - B11 * B02));
      float rf = fminf(1.0f, fmaxf(-1.0f, (float)r));
      const float phi = acosf(rf) * (1.0f / 3.0f);
      e1 = q + 2.0 * pp * (double)cosf(phi);
      e3 = q + 2.0 * pp * (double)cosf(phi + 2.0943951023931953f);
      e2 = 3.0 * q - e1 - e3;
    }
    const double s1 = sqrt(fmax(e1, 0.0));
    const double s2 = sqrt(fmax(e2, 0.0));
    const double s3 = sqrt(fmax(e3, 0.0));

    const double detH =
        H[0][0] * (H[1][1] * H[2][2] - H[1][2] * H[2][1]) -
        H[0][1] * (H[1][0] * H[2][2] - H[1][2] * H[2][0]) +
        H[0][2] * (H[1][0] * H[2][1] - H[1][1] * H[2][0]);
    const double d = (detH > 0.0) ? 1.0 : ((detH < 0.0) ? -1.0 : 0.0);

    const double cost = Sq + Sy - 2.0 * (s1 + s2 + d * s3);
    ws[bs] = (float)(cost / (msum + 1e-6) * (double)scale[bs] *
                     (1.0 / (3.0 * (double)NS * (double)NB)));
  }
}

// Kernel 2: minimal dependent dispatch — sum 384 floats, write out[0].
__global__ __launch_bounds__(64) void sum_kernel(const float* __restrict__ ws,
                                                 float* __restrict__ out) {
  const int lane = threadIdx.x;
  double s = 0.0;
#pragma unroll
  for (int i = 0; i < NBS / 64; ++i) s += (double)ws[i * 64 + lane];
#pragma unroll
  for (int off = 32; off; off >>= 1) s += __shfl_xor(s, off, 64);
  if (lane == 0) out[0] = (float)s;
}

}  // namespace

extern "C" void kernel_launch(void* const* d_in, const int* in_sizes, int n_in,
                              void* d_out, int out_size, void* d_ws, size_t ws_size,
                              hipStream_t stream) {
  const float* pred = (const float*)d_in[0];
  const float* truec = (const float*)d_in[1];
  const int* mask = (const int*)d_in[2];
  const int* dna = (const int*)d_in[3];
  const int* rna = (const int*)d_in[4];
  const int* lig = (const int*)d_in[5];
  const float* scale = (const float*)d_in[6];
  float* ws = (float*)d_ws;
  float* out = (float*)d_out;

  loss_kernel<<<NBS, TPB, 0, stream>>>(pred, truec, mask, dna, rna, lig, scale, ws);
  sum_kernel<<<1, 64, 0, stream>>>(ws, out);
}